// Round 1
// baseline (1004.744 us; speedup 1.0000x reference)
//
#include <hip/hip_runtime.h>
#include <hip/hip_bf16.h>
#include <stdint.h>

// ---------------------------------------------------------------------------
// UnitaryExpert: out = rot_theta(x @ U1^T) @ U2^T + passthrough
// U = I + 2A + 2A^2 + 2A^3 + 2A^4 + 2A^5 + A^6,  A = 0.5(W - W^T)
// Decomposition (skew A => A^T = -A, B := A^2 symmetric):
//   S1 = A*A^T = -B            (BT gemm, X=Y=A)
//   S2 = B*B^T = B^2           (BT gemm, X=Y=B)
//   F  = I + B + B^2 (symmetric)
//   S3 = A*F^T = A + A^3 + A^5 (BT gemm)
//   S4 = B^2*B^T = B^3         (BT gemm)
//   U  = I + 2*S3 - 2*S1 + 2*S2 + S4
// All matmuls (small chain + two big ones) use one bf16 MFMA BT-GEMM kernel
// (m97 recipe: 128x128 tile, BK=32, global_load_lds width=16, 16x16x32 MFMA).
// ---------------------------------------------------------------------------

#define MM (1024 * 1024)

typedef __attribute__((ext_vector_type(4))) float f32x4;
typedef __attribute__((ext_vector_type(8))) short bf16x8;

__device__ __forceinline__ ushort f2bf(float f) {  // round-to-nearest-even
  uint32_t u = __builtin_bit_cast(uint32_t, f);
  u += 0x7FFFu + ((u >> 16) & 1u);
  return (ushort)(u >> 16);
}
__device__ __forceinline__ float bf2f(ushort h) {
  uint32_t u = ((uint32_t)h) << 16;
  return __builtin_bit_cast(float, u);
}

__device__ __forceinline__ void gld_lds16(const ushort* g, ushort* l) {
  // async 16B/lane global->LDS; LDS dest = wave-uniform base + lane*16
  __builtin_amdgcn_global_load_lds(
      (const __attribute__((address_space(1))) unsigned int*)g,
      (__attribute__((address_space(3))) unsigned int*)l, 16, 0, 0);
}

// ---------------------------------------------------------------------------
// BT GEMM: C[m,n] = sum_k X[m,k] * Y[n,k]   (X:[M,K], Y:[N,K], bf16 row-major)
// block = 256 threads (4 waves), tile 128x128, BK=32.
// mode 0: fp32 store to o32 + blockIdx.z*MM (z-batched small matmuls;
//         job = z>>1 selects {X0,Y0} vs {X1,Y1}, mi = z&1 selects matrix)
// mode 1: epilogue pair-rotation by theta, bf16 store to o16
// mode 2: epilogue + passthrough scalar, fp32 store to o32
// ---------------------------------------------------------------------------
__global__ __launch_bounds__(256, 2) void gemm_bt(
    const ushort* __restrict__ X0, const ushort* __restrict__ X1,
    const ushort* __restrict__ Y0, const ushort* __restrict__ Y1,
    float* __restrict__ o32, ushort* __restrict__ o16,
    int M, int N, int K, int mode,
    const float* __restrict__ theta_p, const float* __restrict__ sums) {
  __shared__ ushort lA[128 * 32];
  __shared__ ushort lB[128 * 32];

  const int tid = threadIdx.x;
  const int wave = tid >> 6, lane = tid & 63;
  const int bn = blockIdx.x, bm = blockIdx.y, bz = blockIdx.z;
  const int job = bz >> 1, mi = bz & 1;

  const ushort* X = (job ? X1 : X0) + (size_t)mi * MM;
  const ushort* Y = (job ? Y1 : Y0) + (size_t)mi * MM;

  // staging: thread t loads row (t>>2), k-cols (t&3)*8 .. +8 (16B)
  const ushort* Xg = X + (size_t)(bm * 128 + (tid >> 2)) * K + (tid & 3) * 8;
  const ushort* Yg = Y + (size_t)(bn * 128 + (tid >> 2)) * K + (tid & 3) * 8;
  ushort* lAw = lA + wave * 512;  // wave-uniform LDS base (1024B per wave)
  ushort* lBw = lB + wave * 512;

  const int wm = (wave & 1) * 64;   // wave's 64x64 sub-tile
  const int wn = (wave >> 1) * 64;
  const int lr = lane & 15;         // row (A) / col (B) within 16
  const int kq = (lane >> 4) * 8;   // k offset in elements

  f32x4 acc[4][4] = {};

  for (int k0 = 0; k0 < K; k0 += 32) {
    __syncthreads();
    gld_lds16(Xg + k0, lAw);
    gld_lds16(Xg + k0 + (size_t)64 * K, lAw + 64 * 32);
    gld_lds16(Yg + k0, lBw);
    gld_lds16(Yg + k0 + (size_t)64 * K, lBw + 64 * 32);
    __syncthreads();

    bf16x8 af[4], bfg[4];
#pragma unroll
    for (int t = 0; t < 4; ++t) {
      af[t] = *(const bf16x8*)(lA + (wm + t * 16 + lr) * 32 + kq);
      bfg[t] = *(const bf16x8*)(lB + (wn + t * 16 + lr) * 32 + kq);
    }
#pragma unroll
    for (int ti = 0; ti < 4; ++ti)
#pragma unroll
      for (int tj = 0; tj < 4; ++tj)
        acc[ti][tj] = __builtin_amdgcn_mfma_f32_16x16x32_bf16(
            af[ti], bfg[tj], acc[ti][tj], 0, 0, 0);
  }

  // epilogue: C/D layout col = lane&15, row = (lane>>4)*4 + reg
  const int q4 = (lane >> 4) * 4;
  if (mode == 0) {
    float* O = o32 + (size_t)bz * MM;
#pragma unroll
    for (int ti = 0; ti < 4; ++ti)
#pragma unroll
      for (int r = 0; r < 4; ++r) {
        size_t row = (size_t)(bm * 128 + wm + ti * 16 + q4 + r);
        float* Orow = O + row * N;
#pragma unroll
        for (int tj = 0; tj < 4; ++tj)
          Orow[bn * 128 + wn + tj * 16 + lr] = acc[ti][tj][r];
      }
  } else if (mode == 1) {
    float th = *theta_p, s, c;
    __sincosf(th, &s, &c);
    // even col: c*x0 - s*x1 ; odd col: s*x0 + c*x1 ; partner in lane^1
    const float ssgn = (lane & 1) ? s : -s;
#pragma unroll
    for (int ti = 0; ti < 4; ++ti)
#pragma unroll
      for (int r = 0; r < 4; ++r) {
        size_t row = (size_t)(bm * 128 + wm + ti * 16 + q4 + r);
        ushort* Orow = o16 + row * N;
#pragma unroll
        for (int tj = 0; tj < 4; ++tj) {
          float v = acc[ti][tj][r];
          float w = __shfl_xor(v, 1);
          Orow[bn * 128 + wn + tj * 16 + lr] = f2bf(c * v + ssgn * w);
        }
      }
  } else {
    const float pt = 1e-6f * (sums[0] * (1.0f / 1048576.0f) +
                              sums[1] * (1.0f / 1048576.0f) + *theta_p);
#pragma unroll
    for (int ti = 0; ti < 4; ++ti)
#pragma unroll
      for (int r = 0; r < 4; ++r) {
        size_t row = (size_t)(bm * 128 + wm + ti * 16 + q4 + r);
        float* Orow = o32 + row * N;
#pragma unroll
        for (int tj = 0; tj < 4; ++tj)
          Orow[bn * 128 + wn + tj * 16 + lr] = acc[ti][tj][r] + pt;
      }
  }
}

// ---------------------------------------------------------------------------
// A = 0.5(W - W^T) -> bf16, fused sum(W) reduction (for passthrough mean).
// grid (32,32,2), block (32,8); 32x32 tile, transpose via LDS.
// ---------------------------------------------------------------------------
__global__ __launch_bounds__(256) void prep_a(const float* __restrict__ W1,
                                              const float* __restrict__ W2,
                                              ushort* __restrict__ Abf,
                                              float* __restrict__ sums) {
  __shared__ float sT[32][33];
  const int z = blockIdx.z;
  const float* W = z ? W2 : W1;
  ushort* A = Abf + (size_t)z * MM;
  const int r0 = blockIdx.y * 32, c0 = blockIdx.x * 32;
  const int x = threadIdx.x, y = threadIdx.y;

#pragma unroll
  for (int k = 0; k < 4; ++k)
    sT[y + 8 * k][x] = W[(size_t)(c0 + y + 8 * k) * 1024 + r0 + x];
  __syncthreads();

  float lsum = 0.f;
#pragma unroll
  for (int k = 0; k < 4; ++k) {
    int i = y + 8 * k;
    float w = W[(size_t)(r0 + i) * 1024 + c0 + x];
    lsum += w;
    A[(size_t)(r0 + i) * 1024 + c0 + x] = f2bf(0.5f * (w - sT[x][i]));
  }
#pragma unroll
  for (int off = 32; off > 0; off >>= 1) lsum += __shfl_down(lsum, off);
  if (((y * 32 + x) & 63) == 0) atomicAdd(&sums[z], lsum);
}

// x fp32 -> bf16, vectorized (float4 per thread)
__global__ __launch_bounds__(256) void cvt_x(const float* __restrict__ x,
                                             ushort* __restrict__ xb) {
  const size_t i = (size_t)blockIdx.x * 256 + threadIdx.x;
  float4 v = ((const float4*)x)[i];
  ushort4 o;
  o.x = f2bf(v.x);
  o.y = f2bf(v.y);
  o.z = f2bf(v.z);
  o.w = f2bf(v.w);
  ((ushort4*)xb)[i] = o;
}

// elementwise chain epilogues over 2*MM elements (two matrices)
// mode 0: Bbf = bf16(-S1)
// mode 1: B2bf = bf16(S2); Fbf = bf16(I - S1 + S2)
// mode 2: Ubf = bf16(I - 2*S1 + 2*S2 + 2*S3 + S4)
__global__ __launch_bounds__(256) void ew(const float* __restrict__ S1,
                                          const float* __restrict__ S2,
                                          const float* __restrict__ S3,
                                          const float* __restrict__ S4,
                                          ushort* __restrict__ O0,
                                          ushort* __restrict__ O1, int mode) {
  const int idx = blockIdx.x * 256 + threadIdx.x;  // exactly 2*MM threads
  const int local = idx & (MM - 1);
  const float diag = ((local >> 10) == (local & 1023)) ? 1.f : 0.f;
  if (mode == 0) {
    O0[idx] = f2bf(-S1[idx]);
  } else if (mode == 1) {
    float s2 = S2[idx];
    O0[idx] = f2bf(s2);
    O1[idx] = f2bf(diag - S1[idx] + s2);
  } else {
    O0[idx] =
        f2bf(diag - 2.f * S1[idx] + 2.f * S2[idx] + 2.f * S3[idx] + S4[idx]);
  }
}

extern "C" void kernel_launch(void* const* d_in, const int* in_sizes, int n_in,
                              void* d_out, int out_size, void* d_ws,
                              size_t ws_size, hipStream_t stream) {
  const float* xin = (const float*)d_in[0];
  const float* w1 = (const float*)d_in[1];
  const float* w2 = (const float*)d_in[2];
  const float* th = (const float*)d_in[3];
  float* out = (float*)d_out;

  // workspace carve (all 256B-aligned)
  char* w = (char*)d_ws;
  float* sums = (float*)w;                       // 8 B
  ushort* Abf = (ushort*)(w + 256);              // 2*MM bf16 = 4 MB
  ushort* Bbf = Abf + 2 * MM;                    // 4 MB
  ushort* B2bf = Bbf + 2 * MM;                   // 4 MB
  ushort* Fbf = B2bf + 2 * MM;                   // 4 MB
  ushort* Ubf = Fbf + 2 * MM;                    // 4 MB (U1, U2)
  float* S1 = (float*)(Ubf + 2 * MM);            // 8 MB
  float* S2 = S1 + 2 * MM;                       // 8 MB
  float* S34 = S2 + 2 * MM;                      // 16 MB (S3: z0,1 / S4: z2,3)
  ushort* xbf = (ushort*)(S34 + 4 * MM);         // 128 MB
  ushort* hbf = xbf + (size_t)65536 * 1024;      // 128 MB

  hipMemsetAsync(sums, 0, 2 * sizeof(float), stream);

  prep_a<<<dim3(32, 32, 2), dim3(32, 8), 0, stream>>>(w1, w2, Abf, sums);
  cvt_x<<<65536, 256, 0, stream>>>(xin, xbf);

  // S1 = A*A^T
  gemm_bt<<<dim3(8, 8, 2), 256, 0, stream>>>(Abf, Abf, Abf, Abf, S1, nullptr,
                                             1024, 1024, 1024, 0, th, sums);
  ew<<<8192, 256, 0, stream>>>(S1, S2, S34, S34 + 2 * MM, Bbf, nullptr, 0);
  // S2 = B*B^T = B^2
  gemm_bt<<<dim3(8, 8, 2), 256, 0, stream>>>(Bbf, Bbf, Bbf, Bbf, S2, nullptr,
                                             1024, 1024, 1024, 0, th, sums);
  ew<<<8192, 256, 0, stream>>>(S1, S2, S34, S34 + 2 * MM, B2bf, Fbf, 1);
  // S3 = A*F^T (z0,1) ; S4 = B2*B^T (z2,3)
  gemm_bt<<<dim3(8, 8, 4), 256, 0, stream>>>(Abf, B2bf, Fbf, Bbf, S34, nullptr,
                                             1024, 1024, 1024, 0, th, sums);
  ew<<<8192, 256, 0, stream>>>(S1, S2, S34, S34 + 2 * MM, Ubf, nullptr, 2);

  // h = rot_theta(x @ U1^T)  -> bf16
  gemm_bt<<<dim3(8, 512, 1), 256, 0, stream>>>(xbf, xbf, Ubf, Ubf, nullptr,
                                               hbf, 65536, 1024, 1024, 1, th,
                                               sums);
  // out = h @ U2^T + passthrough -> fp32
  gemm_bt<<<dim3(8, 512, 1), 256, 0, stream>>>(hbf, hbf, Ubf + MM, Ubf + MM,
                                               out, nullptr, 65536, 1024, 1024,
                                               2, th, sums);
}